// Round 3
// baseline (571.026 us; speedup 1.0000x reference)
//
#include <hip/hip_runtime.h>
#include <stdint.h>

// ---------------------------------------------------------------------------
// MiniAlignDecoder on MI355X (gfx950)  — Round 8
// R8 changes vs R7 (gemm_mx now the top steady-state dispatch, 2x94.9 µs,
// MfmaUtil 31% = the known 2-barrier-per-K-step structural ceiling):
//  * gemm_mx rewritten as 256x256-tile, 8-wave (2Mx4N), BK=128, 8-phase
//    schedule with counted vmcnt (T3+T4), raw s_barrier, lgkmcnt(0)+
//    sched_barrier(0) per phase, setprio(1) around MFMA clusters (T5).
//    vmcnt(8) at tile top (never 0 in-loop): the prefetched tile's 8
//    global_load_lds stay in flight across barriers. Double-buffered
//    128 KB LDS; stage of tile t+2 issued in phase 3 (after the barrier
//    proving all reads of that buffer completed). XOR 16B-chunk swizzle
//    and fragment addressing carried over verbatim from the verified
//    128-tile kernel; MODE1 hyperboloid epilogue re-indexed for 8 M-frags.
//  * prep / attn / label_mlp unchanged from R7.
// ---------------------------------------------------------------------------

typedef unsigned short u16;
typedef unsigned char u8;
typedef __attribute__((ext_vector_type(4))) float f32x4;
typedef __attribute__((ext_vector_type(4))) int i32x4;
typedef __attribute__((ext_vector_type(8))) int i32x8;

#define DEVI static __device__ __forceinline__

DEVI float bf2f(u16 u) { return __uint_as_float(((unsigned int)u) << 16); }
DEVI u16 f2bfbits(float f) {
  unsigned int x = __float_as_uint(f);
  unsigned int r = x + 0x7fffu + ((x >> 16) & 1u);   // RNE
  return (u16)(r >> 16);
}
DEVI u8 f2fp8(float f) {
  return (u8)(__builtin_amdgcn_cvt_pk_fp8_f32(f, 0.f, 0, false) & 0xff);
}
DEVI unsigned int pack4_fp8(float a, float b, float c, float d) {
  int r = __builtin_amdgcn_cvt_pk_fp8_f32(a, b, 0, false);
  r = __builtin_amdgcn_cvt_pk_fp8_f32(c, d, r, true);
  return (unsigned int)r;
}

typedef __attribute__((address_space(1))) unsigned int gu32;
typedef __attribute__((address_space(3))) unsigned int su32;
DEVI void lds_cp16(const void* g, void* l) {
  __builtin_amdgcn_global_load_lds((gu32*)g, (su32*)l, 16, 0, 0);
}

// ---------------------------------------------------------------------------
// prep: heterogeneous roles by blockIdx.x (unchanged)
__global__ __launch_bounds__(256) void prep_kernel(
    const float* __restrict__ e, const float* __restrict__ w1,
    const float* __restrict__ w2, const float* __restrict__ b2,
    const float* __restrict__ hw, const float* __restrict__ hb,
    const float* __restrict__ label,
    u8* __restrict__ e8, u8* __restrict__ w1T8, u8* __restrict__ w2eT8,
    float* __restrict__ beff, u16* __restrict__ lh0, u16* __restrict__ lhg) {
  __shared__ float t[64][65];
  const int blk = blockIdx.x;
  const int tid = threadIdx.x;

  if (blk >= 673) {                       // ---- cvt e -> fp8
    int gi = (blk - 673) * 256 + tid;     // uint4 output index
    const float4* in = (const float4*)e + (size_t)gi * 4;
    float4 f0 = in[0], f1 = in[1], f2 = in[2], f3 = in[3];
    uint4 o;
    o.x = pack4_fp8(f0.x, f0.y, f0.z, f0.w);
    o.y = pack4_fp8(f1.x, f1.y, f1.z, f1.w);
    o.z = pack4_fp8(f2.x, f2.y, f2.z, f2.w);
    o.w = pack4_fp8(f3.x, f3.y, f3.z, f3.w);
    ((uint4*)e8)[gi] = o;
  } else if (blk < 512) {                 // ---- transpose w1 -> w1T8 (x32)
    int c0 = (blk & 31) * 64, r0 = (blk >> 5) * 64;
    int tx = tid & 63, ty = tid >> 6;
#pragma unroll
    for (int i = 0; i < 16; i++) {
      int r = i * 4 + ty;
      t[r][tx] = w1[(size_t)(r0 + r) * 2048 + c0 + tx];
    }
    __syncthreads();
#pragma unroll
    for (int i = 0; i < 16; i++) {
      int c = i * 4 + ty;
      w1T8[(size_t)(c0 + c) * 1024 + r0 + tx] = f2fp8(t[tx][c] * 32.f);
    }
  } else if (blk < 640) {                 // ---- w2eff (x64)
    int bw = blk - 512;
    int ch = bw >> 3, kb = bw & 7;
    int k = kb * 256 + tid;
    float row[64];
    const float4* rp = (const float4*)(w2 + (size_t)k * 1024 + ch * 64);
#pragma unroll
    for (int i = 0; i < 16; i++) {
      float4 f = rp[i];
      row[i * 4] = f.x; row[i * 4 + 1] = f.y; row[i * 4 + 2] = f.z; row[i * 4 + 3] = f.w;
    }
    for (int o = 0; o < 64; o++) {
      float a = 0.f;
#pragma unroll
      for (int d = 0; d < 64; d++) a = fmaf(row[d], hw[d * 64 + o], a);
      w2eT8[(size_t)(ch * 64 + o) * 2048 + k] = f2fp8(a * 64.f);
    }
  } else if (blk == 640) {                // ---- beff
    for (int n = tid; n < 1024; n += 256) {
      int ch = n >> 6, o = n & 63;
      float a = hb[o];
#pragma unroll
      for (int d = 0; d < 64; d++) a += b2[ch * 64 + d] * hw[d * 64 + o];
      beff[n] = a;
    }
  } else {                                // ---- lh (bf16, group-of-8 layout)
    int l = (blk - 641) * 256 + tid;
    const float4* lp = (const float4*)(label + (size_t)l * 64);
    float v[64]; float sq = 0.f;
#pragma unroll
    for (int i = 0; i < 16; i++) {
      float4 f = lp[i];
      v[i * 4] = f.x; v[i * 4 + 1] = f.y; v[i * 4 + 2] = f.z; v[i * 4 + 3] = f.w;
      sq += f.x * f.x + f.y * f.y + f.z * f.z + f.w * f.w;
    }
    float dd = fmaxf(1.f - sq, 1e-12f);
    lh0[l] = f2bfbits((1.f + sq) / dd);
    float sc = 2.f / dd;
#pragma unroll
    for (int g = 0; g < 8; g++) {
      unsigned int o0 = f2bfbits(v[8 * g + 0] * sc) | ((unsigned int)f2bfbits(v[8 * g + 1] * sc) << 16);
      unsigned int o1 = f2bfbits(v[8 * g + 2] * sc) | ((unsigned int)f2bfbits(v[8 * g + 3] * sc) << 16);
      unsigned int o2 = f2bfbits(v[8 * g + 4] * sc) | ((unsigned int)f2bfbits(v[8 * g + 5] * sc) << 16);
      unsigned int o3 = f2bfbits(v[8 * g + 6] * sc) | ((unsigned int)f2bfbits(v[8 * g + 7] * sc) << 16);
      ((uint4*)lhg)[(size_t)g * 8192 + l] = make_uint4(o0, o1, o2, o3);
    }
  }
}

// ---------------------------------------------------------------------------
// MX-scaled fp8 GEMM, 256x256 tile, 8 waves (2Mx4N), BK=128, 8-phase
// counted-vmcnt schedule. Per wave: 128x64 output = 8x4 frags of
// 16x16x128 MFMA, 4 phases of 8 MFMA per K-tile. LDS: 2 x (A 32K + B 32K)
// = 128 KB, XOR 16B-chunk swizzle (pos = chunk ^ (row&7)) as before.
// vmcnt(8) at tile top (one prefetched tile in flight), vmcnt(0) only on
// the last tile. Stage of tile t+2 issued in phase 3.
// MODE 0: relu(acc+bias) -> C fp8.  MODE 1: expmap0+hyperboloid -> khg/kh0.
template <int MODE>
__global__ __launch_bounds__(512, 2) void gemm_mx(
    const u8* __restrict__ A, const u8* __restrict__ Bt,
    const float* __restrict__ bias, u8* __restrict__ C,
    u16* __restrict__ khg, u16* __restrict__ kh0,
    int N, int K, unsigned int sb_scale) {
  __shared__ __attribute__((aligned(16))) u8 SM[131072];
  const int tid = threadIdx.x;
  const int wave = tid >> 6, lane = tid & 63;
  const int fr = lane & 15, q = lane >> 4;
  const int nblk = N >> 8;
  const int g = blockIdx.x;
  const int xcd = g & 7;
  const int tt = g >> 3;
  const int per = (gridDim.x >> 3) / nblk;     // bm rows per XCD
  const int bm = xcd * per + tt / nblk;
  const int bn = tt % nblk;
  const size_t m0 = (size_t)bm * 256;
  const int n0 = bn * 256;
  const int wm = (wave >> 2) << 7;             // 0 / 128
  const int wn = (wave & 3) << 6;              // 0 / 64 / 128 / 192
  f32x4 acc[8][4] = {};

  // staging: call c covers rows [c*64, c*64+64); thread: row = c*64+(tid>>3),
  // LDS pos = tid&7, source chunk = pos ^ (row&7)
  const int srow8 = tid >> 3;
  const int schunk = (tid & 7) ^ (srow8 & 7);
  const u8* Ap = A + (m0 + srow8) * (size_t)K + schunk * 16;
  const u8* Bp = Bt + ((size_t)n0 + srow8) * K + schunk * 16;
  const int ldsw = wave * 1024;

  // fragment read base: row = wm|wn + f*16 + fr, lo chunk pos = (2q)^(fr&7)
  const int swz = (((q << 1)) ^ (fr & 7)) << 4;
  const int aoff = (wm + fr) * 128 + swz;
  const int boff = (wn + fr) * 128 + swz;

#define STAGE(q_, kk_)                                                     \
  {                                                                        \
    u8* as_ = SM + (q_) * 65536;                                           \
    u8* bs_ = SM + (q_) * 65536 + 32768;                                   \
    const u8* ag_ = Ap + (kk_);                                            \
    const u8* bg_ = Bp + (kk_);                                            \
    lds_cp16(ag_, as_ + ldsw);                                             \
    lds_cp16(bg_, bs_ + ldsw);                                             \
    lds_cp16(ag_ + (size_t)64 * K, as_ + 8192 + ldsw);                     \
    lds_cp16(bg_ + (size_t)64 * K, bs_ + 8192 + ldsw);                     \
    lds_cp16(ag_ + (size_t)128 * K, as_ + 16384 + ldsw);                   \
    lds_cp16(bg_ + (size_t)128 * K, bs_ + 16384 + ldsw);                   \
    lds_cp16(ag_ + (size_t)192 * K, as_ + 24576 + ldsw);                   \
    lds_cp16(bg_ + (size_t)192 * K, bs_ + 24576 + ldsw);                   \
  }

#define LDFRAG(dst, base, off)                                             \
  {                                                                        \
    i32x4 lo_ = *(const i32x4*)((base) + (off));                           \
    i32x4 hi_ = *(const i32x4*)((base) + ((off) ^ 16));                    \
    dst = __builtin_shufflevector(lo_, hi_, 0, 1, 2, 3, 4, 5, 6, 7);       \
  }

#define MFMA_CLUSTER(mb, nb)                                               \
  __builtin_amdgcn_s_setprio(1);                                           \
  _Pragma("unroll") for (int mi = 0; mi < 4; mi++)                         \
      _Pragma("unroll") for (int ni = 0; ni < 2; ni++)                     \
          acc[(mb) + mi][(nb) + ni] =                                      \
      __builtin_amdgcn_mfma_scale_f32_16x16x128_f8f6f4(                    \
          af[mi], bf[(nb) + ni], acc[(mb) + mi][(nb) + ni], 0, 0,          \
          0, 0x7F7F7F7F, 0, (int)sb_scale);                                \
  __builtin_amdgcn_s_setprio(0);

#define BAR() __builtin_amdgcn_s_barrier()
#define SFENCE() __builtin_amdgcn_sched_barrier(0)
#define LGKM0()                                               \
  asm volatile("s_waitcnt lgkmcnt(0)" ::: "memory");          \
  SFENCE()

  const int NT = K >> 7;
  STAGE(0, 0);
  STAGE(1, 128);
  i32x8 af[4], bf[4];

  for (int t2 = 0; t2 < NT; t2++) {
    const int cur = t2 & 1;
    const u8* as_ = SM + cur * 65536;
    const u8* bs_ = SM + cur * 65536 + 32768;
    // ---- tile top: current tile's 8 loads landed; prefetched tile stays
    //      in flight (vmcnt(8)); drain fully only on the last tile.
    if (t2 + 1 < NT) {
      asm volatile("s_waitcnt vmcnt(8)" ::: "memory");
    } else {
      asm volatile("s_waitcnt vmcnt(0)" ::: "memory");
    }
    SFENCE();
    BAR();
    SFENCE();
    // ---- P0: read A m0..3 + B n0..1; MFMA (m0..3 x n0..1)
    LDFRAG(af[0], as_, aoff);
    LDFRAG(af[1], as_, aoff + 2048);
    LDFRAG(af[2], as_, aoff + 4096);
    LDFRAG(af[3], as_, aoff + 6144);
    LDFRAG(bf[0], bs_, boff);
    LDFRAG(bf[1], bs_, boff + 2048);
    BAR();
    LGKM0();
    MFMA_CLUSTER(0, 0);
    SFENCE();
    BAR();
    SFENCE();
    // ---- P1: read B n2..3; MFMA (m0..3 x n2..3)
    LDFRAG(bf[2], bs_, boff + 4096);
    LDFRAG(bf[3], bs_, boff + 6144);
    BAR();
    LGKM0();
    MFMA_CLUSTER(0, 2);
    SFENCE();
    BAR();
    SFENCE();
    // ---- P2: read A m4..7 (overwrite af); MFMA (m4..7 x n2..3)
    LDFRAG(af[0], as_, aoff + 8192);
    LDFRAG(af[1], as_, aoff + 10240);
    LDFRAG(af[2], as_, aoff + 12288);
    LDFRAG(af[3], as_, aoff + 14336);
    BAR();
    LGKM0();
    MFMA_CLUSTER(4, 2);
    SFENCE();
    BAR();
    SFENCE();
    // ---- P3: stage tile t+2 into buf[cur] (all reads of it are done,
    //      chip-wide, per P2's closing barrier); MFMA (m4..7 x n0..1)
    if (t2 + 2 < NT) STAGE(cur, (size_t)(t2 + 2) * 128);
    MFMA_CLUSTER(4, 0);
    SFENCE();
  }

  // C/D layout: col = n0+wn+n*16+fr, row = m0+wm+i*16+q*4+r  [m89-verified]
  if constexpr (MODE == 0) {
#pragma unroll
    for (int n = 0; n < 4; n++) {
      int col = n0 + wn + n * 16 + fr;
      float bv = bias[col];
#pragma unroll
      for (int i = 0; i < 8; i++) {
#pragma unroll
        for (int r = 0; r < 4; r++) {
          size_t row = m0 + wm + i * 16 + q * 4 + r;
          C[row * N + col] = f2fp8(fmaxf(acc[i][n][r] + bv, 0.f));
        }
      }
    }
  } else {
    // fused expmap0 + hyperboloid; wave's 64 cols = one full head,
    // wave's 128 rows = s0..s0+127. SM reused (last tile read buf1; this
    // region is buf0; all DMA drained by the last tile's vmcnt(0)).
    // ew: per wave 16 cols x 130 rows u16 (stride 130 breaks bank align),
    // k0w: per wave 128 u16 at byte 33280.
    u16* ew = (u16*)SM;
    u16* k0w = (u16*)(SM + 33280);
    const int head = (n0 + wn) >> 6;
    const int rb = (int)m0 + wm;
    const int b = rb >> 10, s0 = rb & 1023;
    u16* gbase = khg + (size_t)(b * 16 + head) * 65536;   // [8][1024][8] u16
    float bv[4];
#pragma unroll
    for (int n = 0; n < 4; n++) bv[n] = bias[n0 + wn + n * 16 + fr];

    float ff[8][4];
#pragma unroll
    for (int i = 0; i < 8; i++) {
#pragma unroll
      for (int r = 0; r < 4; r++) {
        float v0 = acc[i][0][r] + bv[0];
        float v1 = acc[i][1][r] + bv[1];
        float v2 = acc[i][2][r] + bv[2];
        float v3 = acc[i][3][r] + bv[3];
        float ss = v0 * v0 + v1 * v1 + v2 * v2 + v3 * v3;
        ss += __shfl_xor(ss, 1); ss += __shfl_xor(ss, 2);
        ss += __shfl_xor(ss, 4); ss += __shfl_xor(ss, 8);  // 64-dim norm^2
        float n = sqrtf(fmaxf(ss, 1e-12f));
        float ex = __expf(-2.f * n);
        float th = (1.f - ex) / (1.f + ex);                // tanh(n)
        float sq = th * th;
        float dd = fmaxf(1.f - sq, 1e-12f);
        ff[i][r] = 2.f * (th / n) / dd;
        if (fr == 0) k0w[wave * 128 + i * 16 + q * 4 + r] = f2bfbits((1.f + sq) / dd);
      }
    }
#pragma unroll
    for (int n = 0; n < 4; n++) {
#pragma unroll
      for (int i = 0; i < 8; i++)
#pragma unroll
        for (int r = 0; r < 4; r++) {
          int trow = i * 16 + q * 4 + r;
          ew[wave * 2080 + fr * 130 + trow] =
              f2bfbits((acc[i][n][r] + bv[n]) * ff[i][r]);
        }
      __syncthreads();
      // store groups 2n, 2n+1: row halves it2, one uint4 = 8 comps
#pragma unroll
      for (int it = 0; it < 2; it++) {
#pragma unroll
        for (int it2 = 0; it2 < 2; it2++) {
          const u16* eb = ew + wave * 2080 + it * 8 * 130 + it2 * 64 + lane;
          unsigned int o0 = eb[0]   | ((unsigned int)eb[130] << 16);
          unsigned int o1 = eb[260] | ((unsigned int)eb[390] << 16);
          unsigned int o2 = eb[520] | ((unsigned int)eb[650] << 16);
          unsigned int o3 = eb[780] | ((unsigned int)eb[910] << 16);
          *(uint4*)(gbase +
                    ((size_t)(n * 2 + it) * 1024 + s0 + it2 * 64 + lane) * 8) =
              make_uint4(o0, o1, o2, o3);
        }
      }
      __syncthreads();
    }
    {
      unsigned int dat = ((const unsigned int*)k0w)[wave * 64 + lane];
      *(unsigned int*)(kh0 + (size_t)(b * 16 + head) * 1024 + s0 + lane * 2) = dat;
    }
  }
#undef STAGE
#undef LDFRAG
#undef MFMA_CLUSTER
#undef BAR
#undef SFENCE
#undef LGKM0
}

// ---------------------------------------------------------------------------
// attention, register-resident kh; preload is 32 uint4 + 4 u16 loads/thread
__global__ __launch_bounds__(256, 2) void attn_kernel(
    const u16* __restrict__ khg, const u16* __restrict__ kh0,
    const float* __restrict__ label,
    const int* __restrict__ y, const int* __restrict__ mask_text,
    float* __restrict__ qh_out) {
  const int g = blockIdx.x;
  const int b = (g & 7) * 4 + ((g >> 3) & 3);
  const int h = g >> 5;
  const int bh = b * 16 + h;
  const int tid = threadIdx.x, lane = tid & 63, wave = tid >> 6;
  __shared__ float qh[65], rtmp[4], redp[4][65];
  const u16* khb = khg + (size_t)bh * 65536;
  const u16* k0b = kh0 + (size_t)bh * 1024;

  float kh0r[4];
  unsigned int khp[4][32];    // khp[r][k] = (comp 2k+1) | (comp 2k+2)<<16
  int mt[4];
#pragma unroll
  for (int r = 0; r < 4; r++) {
    int s = r * 256 + tid;
    mt[r] = mask_text[b * 1024 + s];
    kh0r[r] = bf2f(k0b[s]);
#pragma unroll
    for (int gg = 0; gg < 8; gg++) {
      uint4 v = *(const uint4*)(khb + ((size_t)gg * 1024 + s) * 8);
      khp[r][gg * 4 + 0] = v.x;
      khp[r][gg * 4 + 1] = v.y;
      khp[r][gg * 4 + 2] = v.z;
      khp[r][gg * 4 + 3] = v.w;
    }
  }

  if (wave == 0) {                         // initial lift of q = label[y[b]]
    float qv = label[(size_t)y[b] * 64 + lane];
    float sq = qv * qv;
#pragma unroll
    for (int d = 1; d < 64; d <<= 1) sq += __shfl_xor(sq, d);
    float dd = fmaxf(1.f - sq, 1e-12f);
    qh[lane + 1] = 2.f * qv / dd;
    if (lane == 0) qh[0] = (1.f + sq) / dd;
  }
  __syncthreads();

  for (int layer = 0; layer < 4; layer++) {
    float q0 = qh[0];
    float inn[4];
#pragma unroll
    for (int r = 0; r < 4; r++) inn[r] = -q0 * kh0r[r];
#pragma unroll
    for (int k = 0; k < 32; k++) {
      float qa = qh[1 + 2 * k], qb = qh[2 + 2 * k];
#pragma unroll
      for (int r = 0; r < 4; r++) {
        unsigned int p = khp[r][k];
        inn[r] = fmaf(qa, __uint_as_float(p << 16),
                 fmaf(qb, __uint_as_float(p & 0xffff0000u), inn[r]));
      }
    }
    float w[4]; float lmax = -3e38f;
#pragma unroll
    for (int r = 0; r < 4; r++) {
      float x = fmaxf(-inn[r], 1.f + 1e-6f);
      float sco = -acoshf(x);
      sco = (mt[r] > 0) ? sco : -1e9f;
      w[r] = sco;
      lmax = fmaxf(lmax, sco);
    }
#pragma unroll
    for (int d = 1; d < 64; d <<= 1) lmax = fmaxf(lmax, __shfl_xor(lmax, d));
    if (lane == 0) rtmp[wave] = lmax;
    __syncthreads();
    float m = fmaxf(fmaxf(rtmp[0], rtmp[1]), fmaxf(rtmp[2], rtmp[3]));
#pragma unroll
    for (int r = 0; r < 4; r++) w[r] = __expf(w[r] - m);

    float p0 = w[0] * kh0r[0] + w[1] * kh0r[1] + w[2] * kh0r[2] + w[3] * kh0r[3];
#pragma unroll
    for (int d = 1; d < 64; d <<= 1) p0 += __shfl_xor(p0, d);
    if (lane == 0) redp[wave][0] = p0;
#pragma unroll
    for (int k = 0; k < 32; k++) {
      float pa = 0.f, pb = 0.f;
#pragma unroll
      for (int r = 0; r < 4; r++) {
        unsigned int p = khp[r][k];
        pa = fmaf(w[r], __uint_as_float(p << 16), pa);
        pb = fmaf(w[r], __uint_as_float(p & 0xffff0000u), pb);
      }
#pragma unroll
      for (int d = 1; d < 64; d <<= 1) pa += __shfl_xor(pa, d);
#pragma unroll
      for (int d = 1; d < 64; d <<= 1) pb += __shfl_xor(pb, d);
      if (lane == 0) { redp[wave][1 + 2 * k] = pa; redp[wave][2 + 2 * k] = pb; }
    }
    __syncthreads();

    if (wave == 0) {                       // Einstein midpoint + k2p + lift
      float denom = redp[0][0] + redp[1][0] + redp[2][0] + redp[3][0];
      float num = redp[0][lane + 1] + redp[1][lane + 1] + redp[2][lane + 1] + redp[3][lane + 1];
      float mid = num / denom;             // Klein coords
      float kl = mid * mid;
#pragma unroll
      for (int d = 1; d < 64; d <<= 1) kl += __shfl_xor(kl, d);
      float u = sqrtf(fmaxf(1.f - kl, 1e-12f));
      float pc = mid / (1.f + u);
      float sp = kl / ((1.f + u) * (1.f + u));
      float dd = fmaxf(1.f - sp, 1e-12f);
      qh[lane + 1] = 2.f * pc / dd;
      if (lane == 0) qh[0] = (1.f + sp) / dd;
    }
    __syncthreads();
  }
  if (tid < 65) qh_out[(size_t)bh * 65 + tid] = qh[tid];
}

// ---------------------------------------------------------------------------
// label distances + aggregation MLP; lh loads are 8 uint4/thread
__global__ __launch_bounds__(256) void label_mlp(
    const float* __restrict__ qh, const u16* __restrict__ lh0,
    const u16* __restrict__ lhg,
    const float* __restrict__ w1, const float* __restrict__ b1,
    const float* __restrict__ w2, const float* __restrict__ b2,
    const float* __restrict__ w3, const float* __restrict__ b3,
    const float* __restrict__ w4, const float* __restrict__ b4,
    const int* __restrict__ mask_label, float* __restrict__ out) {
  int blk = blockIdx.x;
  int b = blk >> 5, lb = blk & 31;
  int l = lb * 256 + threadIdx.x;
  const float* qb = qh + (size_t)b * 1040;

  float inner[16];
  float l0 = bf2f(lh0[l]);
#pragma unroll
  for (int h = 0; h < 16; h++) inner[h] = -qb[h * 65] * l0;
#pragma unroll
  for (int g = 0; g < 8; g++) {
    uint4 v = *(const uint4*)(lhg + ((size_t)g * 8192 + l) * 8);
    unsigned int pw[4] = {v.x, v.y, v.z, v.w};
#pragma unroll
    for (int p = 0; p < 4; p++) {
      int k = g * 4 + p;
      float la = __uint_as_float(pw[p] << 16);
      float lb2 = __uint_as_float(pw[p] & 0xffff0000u);
#pragma unroll
      for (int h = 0; h < 16; h++)
        inner[h] = fmaf(qb[h * 65 + 1 + 2 * k], la,
                   fmaf(qb[h * 65 + 2 + 2 * k], lb2, inner[h]));
    }
  }
  float d[16];
#pragma unroll
  for (int h = 0; h < 16; h++) d[h] = acoshf(fmaxf(-inner[h], 1.f + 1e-6f));

  float x1[32];
#pragma unroll
  for (int o = 0; o < 32; o++) {
    float a = b1[o];
#pragma unroll
    for (int h = 0; h < 16; h++) a = fmaf(d[h], w1[h * 32 + o], a);
    x1[o] = fmaxf(a, 0.f);
  }
  float x2[32];
#pragma unroll
  for (int o = 0; o < 32; o++) {
    float a = b2[o];
#pragma unroll
    for (int i = 0; i < 32; i++) a = fmaf(x1[i], w2[i * 32 + o], a);
    x2[o] = fmaxf(a, 0.f);
  }
  float x3[16];
#pragma unroll
  for (int o = 0; o < 16; o++) {
    float a = b3[o];
#pragma unroll
    for (int i = 0; i < 32; i++) a = fmaf(x2[i], w3[i * 16 + o], a);
    x3[o] = fmaxf(a, 0.f);
  }
  float acc = b4[0];
#pragma unroll
  for (int h = 0; h < 16; h++) acc = fmaf(x3[h], w4[h], acc);
  out[(size_t)b * 8192 + l] = (mask_label[(size_t)b * 8192 + l] > 0) ? acc : -500.0f;
}

// ---------------------------------------------------------------------------
extern "C" void kernel_launch(void* const* d_in, const int* in_sizes, int n_in,
                              void* d_out, int out_size, void* d_ws, size_t ws_size,
                              hipStream_t stream) {
  const float* e     = (const float*)d_in[0];
  const float* label = (const float*)d_in[1];
  const float* tc_w1 = (const float*)d_in[2];
  const float* tc_b1 = (const float*)d_in[3];
  const float* tc_w2 = (const float*)d_in[4];
  const float* tc_b2 = (const float*)d_in[5];
  const float* hyp_w = (const float*)d_in[6];
  const float* hyp_b = (const float*)d_in[7];
  const float* aw1 = (const float*)d_in[8];
  const float* ab1 = (const float*)d_in[9];
  const float* aw2 = (const float*)d_in[10];
  const float* ab2 = (const float*)d_in[11];
  const float* aw3 = (const float*)d_in[12];
  const float* ab3 = (const float*)d_in[13];
  const float* aw4 = (const float*)d_in[14];
  const float* ab4 = (const float*)d_in[15];
  const int* y          = (const int*)d_in[16];
  const int* mask_text  = (const int*)d_in[17];
  const int* mask_label = (const int*)d_in[18];
  float* out = (float*)d_out;

  char* ws = (char*)d_ws;
  // [0, 67.1MB): X8 (fp8 32768x2048); qh (133KB) aliases it after gemm2
  // [67.1MB, 134.2MB): khg bf16 [512][8][1024][8] (comps 1..64 interleaved)
  // [134.2MB, 135.3MB): kh0 bf16 [512][1024]
  // [135.3MB, 168.8MB): e8 fp8 [32768][1024]
  u8*    X8    = (u8*)(ws + 0);
  float* qh    = (float*)(ws + 0);
  u16*   khg   = (u16*)(ws + 67108864ull);
  u16*   kh0   = (u16*)(ws + 134217728ull);
  u8*    e8    = (u8*)(ws + 135266304ull);
  u8*    w1T8  = (u8*)(ws + 168820736ull);
  u8*    w2eT8 = (u8*)(ws + 170917888ull);
  float* beff  = (float*)(ws + 173015040ull);
  u16*   lhg   = (u16*)(ws + 173019136ull);   // bf16 [8][8192][8] = 1.0MB
  u16*   lh0   = (u16*)(ws + 174067712ull);   // bf16 [8192] = 16KB

  prep_kernel<<<673 + 8192, 256, 0, stream>>>(e, tc_w1, tc_w2, tc_b2, hyp_w, hyp_b,
                                              label, e8, w1T8, w2eT8, beff, lh0, lhg);
  // scale B bytes (E8M0, replicated): 0x7A = 2^-5 (cancels w1 x32),
  // 0x79 = 2^-6 (cancels w2eff x64)
  gemm_mx<0><<<1024, 512, 0, stream>>>(e8, w1T8, tc_b1, X8, nullptr, nullptr,
                                       2048, 1024, 0x7A7A7A7Au);
  gemm_mx<1><<<512, 512, 0, stream>>>(X8, w2eT8, beff, nullptr, khg, kh0,
                                      1024, 2048, 0x79797979u);
  attn_kernel<<<512, 256, 0, stream>>>(khg, kh0, label, y, mask_text, qh);
  label_mlp<<<1024, 256, 0, stream>>>(qh, lh0, lhg, aw1, ab1, aw2, ab2, aw3, ab3,
                                      aw4, ab4, mask_label, out);
}

// Round 5
// 529.459 us; speedup vs baseline: 1.0785x; 1.0785x over previous
//
#include <hip/hip_runtime.h>
#include <stdint.h>

// ---------------------------------------------------------------------------
// MiniAlignDecoder on MI355X (gfx950)  — Round 9 (resubmit; R4 bench was an
// infra failure "container failed twice", no counters returned)
// R9 changes vs R8 (8-phase 256² port REGRESSED: 117 µs vs 94.9, occupancy
// 21% (1 blk/CU lockstep), MfmaUtil 24% — burst-staged vmcnt(8) lead time
// < HBM latency; matches the m232 OPEN-quadrant null):
//  * gemm_mx REVERTED to the verified 128²-tile 2-barrier structure
//    (R7 code: 94.9 µs, MfmaUtil 31%, occ 37% = structure ceiling).
//  * label_mlp: q-vector (1040 f32) staged TRANSPOSED into LDS qT[65][16]
//    once per block (coalesced), inner loop reads contiguous 16-float rows
//    -> ds_read_b128 broadcast, replacing ~1024 scalar global qb loads per
//    thread (suspected hidden ~90 µs VMEM-issue bottleneck just under the
//    top-5 cutoff).
//  * prep / attn unchanged from R7.
// ---------------------------------------------------------------------------

typedef unsigned short u16;
typedef unsigned char u8;
typedef __attribute__((ext_vector_type(4))) float f32x4;
typedef __attribute__((ext_vector_type(4))) int i32x4;
typedef __attribute__((ext_vector_type(8))) int i32x8;

#define DEVI static __device__ __forceinline__

DEVI float bf2f(u16 u) { return __uint_as_float(((unsigned int)u) << 16); }
DEVI u16 f2bfbits(float f) {
  unsigned int x = __float_as_uint(f);
  unsigned int r = x + 0x7fffu + ((x >> 16) & 1u);   // RNE
  return (u16)(r >> 16);
}
DEVI u8 f2fp8(float f) {
  return (u8)(__builtin_amdgcn_cvt_pk_fp8_f32(f, 0.f, 0, false) & 0xff);
}
DEVI unsigned int pack4_fp8(float a, float b, float c, float d) {
  int r = __builtin_amdgcn_cvt_pk_fp8_f32(a, b, 0, false);
  r = __builtin_amdgcn_cvt_pk_fp8_f32(c, d, r, true);
  return (unsigned int)r;
}

typedef __attribute__((address_space(1))) unsigned int gu32;
typedef __attribute__((address_space(3))) unsigned int su32;
DEVI void lds_cp16(const void* g, void* l) {
  __builtin_amdgcn_global_load_lds((gu32*)g, (su32*)l, 16, 0, 0);
}

// ---------------------------------------------------------------------------
// prep: heterogeneous roles by blockIdx.x (unchanged from R7)
__global__ __launch_bounds__(256) void prep_kernel(
    const float* __restrict__ e, const float* __restrict__ w1,
    const float* __restrict__ w2, const float* __restrict__ b2,
    const float* __restrict__ hw, const float* __restrict__ hb,
    const float* __restrict__ label,
    u8* __restrict__ e8, u8* __restrict__ w1T8, u8* __restrict__ w2eT8,
    float* __restrict__ beff, u16* __restrict__ lh0, u16* __restrict__ lhg) {
  __shared__ float t[64][65];
  const int blk = blockIdx.x;
  const int tid = threadIdx.x;

  if (blk >= 673) {                       // ---- cvt e -> fp8
    int gi = (blk - 673) * 256 + tid;     // uint4 output index
    const float4* in = (const float4*)e + (size_t)gi * 4;
    float4 f0 = in[0], f1 = in[1], f2 = in[2], f3 = in[3];
    uint4 o;
    o.x = pack4_fp8(f0.x, f0.y, f0.z, f0.w);
    o.y = pack4_fp8(f1.x, f1.y, f1.z, f1.w);
    o.z = pack4_fp8(f2.x, f2.y, f2.z, f2.w);
    o.w = pack4_fp8(f3.x, f3.y, f3.z, f3.w);
    ((uint4*)e8)[gi] = o;
  } else if (blk < 512) {                 // ---- transpose w1 -> w1T8 (x32)
    int c0 = (blk & 31) * 64, r0 = (blk >> 5) * 64;
    int tx = tid & 63, ty = tid >> 6;
#pragma unroll
    for (int i = 0; i < 16; i++) {
      int r = i * 4 + ty;
      t[r][tx] = w1[(size_t)(r0 + r) * 2048 + c0 + tx];
    }
    __syncthreads();
#pragma unroll
    for (int i = 0; i < 16; i++) {
      int c = i * 4 + ty;
      w1T8[(size_t)(c0 + c) * 1024 + r0 + tx] = f2fp8(t[tx][c] * 32.f);
    }
  } else if (blk < 640) {                 // ---- w2eff (x64)
    int bw = blk - 512;
    int ch = bw >> 3, kb = bw & 7;
    int k = kb * 256 + tid;
    float row[64];
    const float4* rp = (const float4*)(w2 + (size_t)k * 1024 + ch * 64);
#pragma unroll
    for (int i = 0; i < 16; i++) {
      float4 f = rp[i];
      row[i * 4] = f.x; row[i * 4 + 1] = f.y; row[i * 4 + 2] = f.z; row[i * 4 + 3] = f.w;
    }
    for (int o = 0; o < 64; o++) {
      float a = 0.f;
#pragma unroll
      for (int d = 0; d < 64; d++) a = fmaf(row[d], hw[d * 64 + o], a);
      w2eT8[(size_t)(ch * 64 + o) * 2048 + k] = f2fp8(a * 64.f);
    }
  } else if (blk == 640) {                // ---- beff
    for (int n = tid; n < 1024; n += 256) {
      int ch = n >> 6, o = n & 63;
      float a = hb[o];
#pragma unroll
      for (int d = 0; d < 64; d++) a += b2[ch * 64 + d] * hw[d * 64 + o];
      beff[n] = a;
    }
  } else {                                // ---- lh (bf16, group-of-8 layout)
    int l = (blk - 641) * 256 + tid;
    const float4* lp = (const float4*)(label + (size_t)l * 64);
    float v[64]; float sq = 0.f;
#pragma unroll
    for (int i = 0; i < 16; i++) {
      float4 f = lp[i];
      v[i * 4] = f.x; v[i * 4 + 1] = f.y; v[i * 4 + 2] = f.z; v[i * 4 + 3] = f.w;
      sq += f.x * f.x + f.y * f.y + f.z * f.z + f.w * f.w;
    }
    float dd = fmaxf(1.f - sq, 1e-12f);
    lh0[l] = f2bfbits((1.f + sq) / dd);
    float sc = 2.f / dd;
#pragma unroll
    for (int g = 0; g < 8; g++) {
      unsigned int o0 = f2bfbits(v[8 * g + 0] * sc) | ((unsigned int)f2bfbits(v[8 * g + 1] * sc) << 16);
      unsigned int o1 = f2bfbits(v[8 * g + 2] * sc) | ((unsigned int)f2bfbits(v[8 * g + 3] * sc) << 16);
      unsigned int o2 = f2bfbits(v[8 * g + 4] * sc) | ((unsigned int)f2bfbits(v[8 * g + 5] * sc) << 16);
      unsigned int o3 = f2bfbits(v[8 * g + 6] * sc) | ((unsigned int)f2bfbits(v[8 * g + 7] * sc) << 16);
      ((uint4*)lhg)[(size_t)g * 8192 + l] = make_uint4(o0, o1, o2, o3);
    }
  }
}

// ---------------------------------------------------------------------------
// MX-scaled fp8 GEMM: K=128/iter, 128x128 tile, 4 waves (2x2), 4x4 MFMA
// 16x16x128 per wave. LDS rows 128 B with XOR 16B-chunk swizzle.
// (verified structure, 94.9 µs steady; reverted from the R8 experiment)
// MODE 0: relu(acc+bias) -> C fp8.
// MODE 1: expmap0+hyperboloid -> khg (group-of-8 interleaved) + kh0.
template <int MODE>
__global__ __launch_bounds__(256, 4) void gemm_mx(
    const u8* __restrict__ A, const u8* __restrict__ Bt,
    const float* __restrict__ bias, u8* __restrict__ C,
    u16* __restrict__ khg, u16* __restrict__ kh0,
    int N, int K, unsigned int sb_scale) {
  __shared__ __attribute__((aligned(16))) u8 SM[32768];
  u8* As = SM;                 // [128][128] fp8, chunk-swizzled
  u8* Bs = SM + 16384;
  const int tid = threadIdx.x;
  const int wave = tid >> 6, lane = tid & 63;
  const int fr = lane & 15, q = lane >> 4;
  const int nblk = N >> 7;
  const int g = blockIdx.x;
  const int xcd = g & 7;
  const int t = g >> 3;
  const int per = (gridDim.x >> 3) / nblk;     // bm rows per XCD
  const int bm = xcd * per + t / nblk;
  const int bn = t % nblk;
  const size_t m0 = (size_t)bm * 128;
  const int n0 = bn * 128;
  const int wm = (wave >> 1) << 6, wn = (wave & 1) << 6;
  f32x4 acc[4][4] = {};

  // staging: call c covers rows [c*32, c*32+32); lane: row = c*32 + (tid>>3),
  // LDS pos = tid&7, source chunk = pos ^ (row&7)  (c*32 = 0 mod 8)
  const int srow = tid >> 3;
  const int schunk = (tid & 7) ^ (srow & 7);
  const u8* Ap = A + (m0 + srow) * (size_t)K + schunk * 16;
  const u8* Bp = Bt + ((size_t)n0 + srow) * K + schunk * 16;

  // fragment read base: row = wm|wn + t2*16 + fr (row&7 == fr&7), lane's
  // 32 K-bytes = chunks {2q, 2q+1} -> swizzled positions, hi = lo ^ 16
  const int aL = (wm + fr) * 128 + ((((q << 1)) ^ (fr & 7)) << 4);
  const int bL = (wn + fr) * 128 + ((((q << 1)) ^ (fr & 7)) << 4);

  for (int kk = 0; kk < K; kk += 128) {
#pragma unroll
    for (int c = 0; c < 4; c++) {
      lds_cp16(Ap + (size_t)c * 32 * K, As + c * 4096 + wave * 1024);
      lds_cp16(Bp + (size_t)c * 32 * K, Bs + c * 4096 + wave * 1024);
    }
    Ap += 128; Bp += 128;
    __syncthreads();   // staged data visible
    i32x8 af[4], bf[4];
#pragma unroll
    for (int t2 = 0; t2 < 4; t2++) {
      i32x4 lo = *(const i32x4*)(As + aL + t2 * 2048);
      i32x4 hi = *(const i32x4*)(As + (aL ^ 16) + t2 * 2048);
      af[t2] = __builtin_shufflevector(lo, hi, 0, 1, 2, 3, 4, 5, 6, 7);
      i32x4 lo2 = *(const i32x4*)(Bs + bL + t2 * 2048);
      i32x4 hi2 = *(const i32x4*)(Bs + (bL ^ 16) + t2 * 2048);
      bf[t2] = __builtin_shufflevector(lo2, hi2, 0, 1, 2, 3, 4, 5, 6, 7);
    }
#pragma unroll
    for (int i = 0; i < 4; i++)
#pragma unroll
      for (int j = 0; j < 4; j++)
        acc[i][j] = __builtin_amdgcn_mfma_scale_f32_16x16x128_f8f6f4(
            af[i], bf[j], acc[i][j], 0, 0,            // fmt A=fp8, fmt B=fp8
            0, 0x7F7F7F7F,                            // scale A = 2^0
            0, (int)sb_scale);                        // scale B (replicated)
    __syncthreads();   // all reads done before next stage overwrites
  }

  // C/D layout: col = n0+wn+j*16+fr, row = m0+wm+i*16+q*4+r  [m89-verified]
  if constexpr (MODE == 0) {
#pragma unroll
    for (int j = 0; j < 4; j++) {
      int col = n0 + wn + j * 16 + fr;
      float bv = bias[col];
#pragma unroll
      for (int i = 0; i < 4; i++) {
#pragma unroll
        for (int r = 0; r < 4; r++) {
          size_t row = m0 + wm + i * 16 + q * 4 + r;
          C[row * N + col] = f2fp8(fmaxf(acc[i][j][r] + bv, 0.f));
        }
      }
    }
  } else {
    // fused expmap0 + hyperboloid; wave's 64 cols = one full head.
    // Reuse SM (dead after K-loop's final barrier): ew = [4][16][66] u16
    // (one 16-comp j-pass per wave), k0w = [4][64] u16 at +9216.
    u16* ew = (u16*)SM;
    u16* k0w = (u16*)(SM + 9216);
    const int head = (n0 + wn) >> 6;
    const int rb = (int)m0 + wm;
    const int b = rb >> 10, s0 = rb & 1023;
    u16* gbase = khg + (size_t)(b * 16 + head) * 65536;   // [8][1024][8] u16
    float bv[4];
#pragma unroll
    for (int j = 0; j < 4; j++) bv[j] = bias[n0 + wn + j * 16 + fr];

    float ff[4][4];
#pragma unroll
    for (int i = 0; i < 4; i++) {
#pragma unroll
      for (int r = 0; r < 4; r++) {
        float v0 = acc[i][0][r] + bv[0];
        float v1 = acc[i][1][r] + bv[1];
        float v2 = acc[i][2][r] + bv[2];
        float v3 = acc[i][3][r] + bv[3];
        float ss = v0 * v0 + v1 * v1 + v2 * v2 + v3 * v3;
        ss += __shfl_xor(ss, 1); ss += __shfl_xor(ss, 2);
        ss += __shfl_xor(ss, 4); ss += __shfl_xor(ss, 8);  // 64-dim norm^2
        float n = sqrtf(fmaxf(ss, 1e-12f));
        float ex = __expf(-2.f * n);
        float th = (1.f - ex) / (1.f + ex);                // tanh(n)
        float sq = th * th;
        float dd = fmaxf(1.f - sq, 1e-12f);
        ff[i][r] = 2.f * (th / n) / dd;
        if (fr == 0) k0w[wave * 64 + i * 16 + q * 4 + r] = f2bfbits((1.f + sq) / dd);
      }
    }
#pragma unroll
    for (int j = 0; j < 4; j++) {
#pragma unroll
      for (int i = 0; i < 4; i++)
#pragma unroll
        for (int r = 0; r < 4; r++) {
          int trow = i * 16 + q * 4 + r;
          ew[wave * 1056 + fr * 66 + trow] =
              f2bfbits((acc[i][j][r] + bv[j]) * ff[i][r]);
        }
      __syncthreads();
      // store groups 2j, 2j+1: lane = row, one uint4 = 8 comps (coalesced,
      // 16 B/lane along consecutive s)
#pragma unroll
      for (int it = 0; it < 2; it++) {
        const u16* eb = ew + wave * 1056 + it * 8 * 66 + lane;
        unsigned int o0 = eb[0]   | ((unsigned int)eb[66]  << 16);
        unsigned int o1 = eb[132] | ((unsigned int)eb[198] << 16);
        unsigned int o2 = eb[264] | ((unsigned int)eb[330] << 16);
        unsigned int o3 = eb[396] | ((unsigned int)eb[462] << 16);
        *(uint4*)(gbase + ((size_t)(j * 2 + it) * 1024 + s0 + lane) * 8) =
            make_uint4(o0, o1, o2, o3);
      }
      __syncthreads();
    }
    if (lane < 32) {
      unsigned int dat = *(const unsigned int*)(k0w + wave * 64 + lane * 2);
      *(unsigned int*)(kh0 + (size_t)(b * 16 + head) * 1024 + s0 + lane * 2) = dat;
    }
  }
}

// ---------------------------------------------------------------------------
// attention, register-resident kh; preload is 32 uint4 + 4 u16 loads/thread
__global__ __launch_bounds__(256, 2) void attn_kernel(
    const u16* __restrict__ khg, const u16* __restrict__ kh0,
    const float* __restrict__ label,
    const int* __restrict__ y, const int* __restrict__ mask_text,
    float* __restrict__ qh_out) {
  const int g = blockIdx.x;
  const int b = (g & 7) * 4 + ((g >> 3) & 3);
  const int h = g >> 5;
  const int bh = b * 16 + h;
  const int tid = threadIdx.x, lane = tid & 63, wave = tid >> 6;
  __shared__ float qh[65], rtmp[4], redp[4][65];
  const u16* khb = khg + (size_t)bh * 65536;
  const u16* k0b = kh0 + (size_t)bh * 1024;

  float kh0r[4];
  unsigned int khp[4][32];    // khp[r][k] = (comp 2k+1) | (comp 2k+2)<<16
  int mt[4];
#pragma unroll
  for (int r = 0; r < 4; r++) {
    int s = r * 256 + tid;
    mt[r] = mask_text[b * 1024 + s];
    kh0r[r] = bf2f(k0b[s]);
#pragma unroll
    for (int gg = 0; gg < 8; gg++) {
      uint4 v = *(const uint4*)(khb + ((size_t)gg * 1024 + s) * 8);
      khp[r][gg * 4 + 0] = v.x;
      khp[r][gg * 4 + 1] = v.y;
      khp[r][gg * 4 + 2] = v.z;
      khp[r][gg * 4 + 3] = v.w;
    }
  }

  if (wave == 0) {                         // initial lift of q = label[y[b]]
    float qv = label[(size_t)y[b] * 64 + lane];
    float sq = qv * qv;
#pragma unroll
    for (int d = 1; d < 64; d <<= 1) sq += __shfl_xor(sq, d);
    float dd = fmaxf(1.f - sq, 1e-12f);
    qh[lane + 1] = 2.f * qv / dd;
    if (lane == 0) qh[0] = (1.f + sq) / dd;
  }
  __syncthreads();

  for (int layer = 0; layer < 4; layer++) {
    float q0 = qh[0];
    float inn[4];
#pragma unroll
    for (int r = 0; r < 4; r++) inn[r] = -q0 * kh0r[r];
#pragma unroll
    for (int k = 0; k < 32; k++) {
      float qa = qh[1 + 2 * k], qb = qh[2 + 2 * k];
#pragma unroll
      for (int r = 0; r < 4; r++) {
        unsigned int p = khp[r][k];
        inn[r] = fmaf(qa, __uint_as_float(p << 16),
                 fmaf(qb, __uint_as_float(p & 0xffff0000u), inn[r]));
      }
    }
    float w[4]; float lmax = -3e38f;
#pragma unroll
    for (int r = 0; r < 4; r++) {
      float x = fmaxf(-inn[r], 1.f + 1e-6f);
      float sco = -acoshf(x);
      sco = (mt[r] > 0) ? sco : -1e9f;
      w[r] = sco;
      lmax = fmaxf(lmax, sco);
    }
#pragma unroll
    for (int d = 1; d < 64; d <<= 1) lmax = fmaxf(lmax, __shfl_xor(lmax, d));
    if (lane == 0) rtmp[wave] = lmax;
    __syncthreads();
    float m = fmaxf(fmaxf(rtmp[0], rtmp[1]), fmaxf(rtmp[2], rtmp[3]));
#pragma unroll
    for (int r = 0; r < 4; r++) w[r] = __expf(w[r] - m);

    float p0 = w[0] * kh0r[0] + w[1] * kh0r[1] + w[2] * kh0r[2] + w[3] * kh0r[3];
#pragma unroll
    for (int d = 1; d < 64; d <<= 1) p0 += __shfl_xor(p0, d);
    if (lane == 0) redp[wave][0] = p0;
#pragma unroll
    for (int k = 0; k < 32; k++) {
      float pa = 0.f, pb = 0.f;
#pragma unroll
      for (int r = 0; r < 4; r++) {
        unsigned int p = khp[r][k];
        pa = fmaf(w[r], __uint_as_float(p << 16), pa);
        pb = fmaf(w[r], __uint_as_float(p & 0xffff0000u), pb);
      }
#pragma unroll
      for (int d = 1; d < 64; d <<= 1) pa += __shfl_xor(pa, d);
#pragma unroll
      for (int d = 1; d < 64; d <<= 1) pb += __shfl_xor(pb, d);
      if (lane == 0) { redp[wave][1 + 2 * k] = pa; redp[wave][2 + 2 * k] = pb; }
    }
    __syncthreads();

    if (wave == 0) {                       // Einstein midpoint + k2p + lift
      float denom = redp[0][0] + redp[1][0] + redp[2][0] + redp[3][0];
      float num = redp[0][lane + 1] + redp[1][lane + 1] + redp[2][lane + 1] + redp[3][lane + 1];
      float mid = num / denom;             // Klein coords
      float kl = mid * mid;
#pragma unroll
      for (int d = 1; d < 64; d <<= 1) kl += __shfl_xor(kl, d);
      float u = sqrtf(fmaxf(1.f - kl, 1e-12f));
      float pc = mid / (1.f + u);
      float sp = kl / ((1.f + u) * (1.f + u));
      float dd = fmaxf(1.f - sp, 1e-12f);
      qh[lane + 1] = 2.f * pc / dd;
      if (lane == 0) qh[0] = (1.f + sp) / dd;
    }
    __syncthreads();
  }
  if (tid < 65) qh_out[(size_t)bh * 65 + tid] = qh[tid];
}

// ---------------------------------------------------------------------------
// label distances + aggregation MLP; lh loads are 8 uint4/thread.
// R9: q staged transposed in LDS (qT[c][h]) -> inner loop reads contiguous
// 16-float rows via ds_read (broadcast), replacing ~1024 scalar global
// loads of qb per thread.
__global__ __launch_bounds__(256) void label_mlp(
    const float* __restrict__ qh, const u16* __restrict__ lh0,
    const u16* __restrict__ lhg,
    const float* __restrict__ w1, const float* __restrict__ b1,
    const float* __restrict__ w2, const float* __restrict__ b2,
    const float* __restrict__ w3, const float* __restrict__ b3,
    const float* __restrict__ w4, const float* __restrict__ b4,
    const int* __restrict__ mask_label, float* __restrict__ out) {
  __shared__ float qT[65][16];            // qT[c][h]
  int blk = blockIdx.x;
  int b = blk >> 5, lb = blk & 31;
  int l = lb * 256 + threadIdx.x;
  const float* qb = qh + (size_t)b * 1040;

  for (int i = threadIdx.x; i < 1040; i += 256) {
    int h = i / 65, c = i % 65;
    qT[c][h] = qb[i];                     // coalesced read, one-time scatter
  }
  __syncthreads();

  float inner[16];
  float l0 = bf2f(lh0[l]);
#pragma unroll
  for (int h = 0; h < 16; h++) inner[h] = -qT[0][h] * l0;
#pragma unroll
  for (int g = 0; g < 8; g++) {
    uint4 v = *(const uint4*)(lhg + ((size_t)g * 8192 + l) * 8);
    unsigned int pw[4] = {v.x, v.y, v.z, v.w};
#pragma unroll
    for (int p = 0; p < 4; p++) {
      int k = g * 4 + p;
      float la = __uint_as_float(pw[p] << 16);
      float lb2 = __uint_as_float(pw[p] & 0xffff0000u);
#pragma unroll
      for (int h = 0; h < 16; h++)
        inner[h] = fmaf(qT[1 + 2 * k][h], la,
                   fmaf(qT[2 + 2 * k][h], lb2, inner[h]));
    }
  }
  float d[16];
#pragma unroll
  for (int h = 0; h < 16; h++) d[h] = acoshf(fmaxf(-inner[h], 1.f + 1e-6f));

  float x1[32];
#pragma unroll
  for (int o = 0; o < 32; o++) {
    float a = b1[o];
#pragma unroll
    for (int h = 0; h < 16; h++) a = fmaf(d[h], w1[h * 32 + o], a);
    x1[o] = fmaxf(a, 0.f);
  }
  float x2[32];
#pragma unroll
  for (int o = 0; o < 32; o++) {
    float a = b2[o];
#pragma unroll
    for (int i = 0; i < 32; i++) a = fmaf(x1[i], w2[i * 32 + o], a);
    x2[o] = fmaxf(a, 0.f);
  }
  float x3[16];
#pragma unroll
  for (int o = 0; o < 16; o++) {
    float a = b3[o];
#pragma unroll
    for (int i = 0; i < 32; i++) a = fmaf(x2[i], w3[i * 16 + o], a);
    x3[o] = fmaxf(a, 0.f);
  }
  float acc = b4[0];
#pragma unroll
  for (int h = 0; h < 16; h++) acc = fmaf(x3[h], w4[h], acc);
  out[(size_t)b * 8192 + l] = (mask_label[(size_t)b * 8192 + l] > 0) ? acc : -500.0f;
}

// ---------------------------------------------------------------------------
extern "C" void kernel_launch(void* const* d_in, const int* in_sizes, int n_in,
                              void* d_out, int out_size, void* d_ws, size_t ws_size,
                              hipStream_t stream) {
  const float* e     = (const float*)d_in[0];
  const float* label = (const float*)d_in[1];
  const float* tc_w1 = (const float*)d_in[2];
  const float* tc_b1 = (const float*)d_in[3];
  const float* tc_w2 = (const float*)d_in[4];
  const float* tc_b2 = (const float*)d_in[5];
  const float* hyp_w = (const float*)d_in[6];
  const float* hyp_b = (const float*)d_in[7];
  const float* aw1 = (const float*)d_in[8];
  const float* ab1 = (const float*)d_in[9];
  const float* aw2 = (const float*)d_in[10];
  const float* ab2 = (const float*)d_in[11];
  const float* aw3 = (const float*)d_in[12];
  const float* ab3 = (const float*)d_in[13];
  const float* aw4 = (const float*)d_in[14];
  const float* ab4 = (const float*)d_in[15];
  const int* y          = (const int*)d_in[16];
  const int* mask_text  = (const int*)d_in[17];
  const int* mask_label = (const int*)d_in[18];
  float* out = (float*)d_out;

  char* ws = (char*)d_ws;
  // [0, 67.1MB): X8 (fp8 32768x2048); qh (133KB) aliases it after gemm2
  // [67.1MB, 134.2MB): khg bf16 [512][8][1024][8] (comps 1..64 interleaved)
  // [134.2MB, 135.3MB): kh0 bf16 [512][1024]
  // [135.3MB, 168.8MB): e8 fp8 [32768][1024]
  u8*    X8    = (u8*)(ws + 0);
  float* qh    = (float*)(ws + 0);
  u16*   khg   = (u16*)(ws + 67108864ull);
  u16*   kh0   = (u16*)(ws + 134217728ull);
  u8*    e8    = (u8*)(ws + 135266304ull);
  u8*    w1T8  = (u8*)(ws + 168820736ull);
  u8*    w2eT8 = (u8*)(ws + 170917888ull);
  float* beff  = (float*)(ws + 173015040ull);
  u16*   lhg   = (u16*)(ws + 173019136ull);   // bf16 [8][8192][8] = 1.0MB
  u16*   lh0   = (u16*)(ws + 174067712ull);   // bf16 [8192] = 16KB

  prep_kernel<<<673 + 8192, 256, 0, stream>>>(e, tc_w1, tc_w2, tc_b2, hyp_w, hyp_b,
                                              label, e8, w1T8, w2eT8, beff, lh0, lhg);
  // scale B bytes (E8M0, replicated): 0x7A = 2^-5 (cancels w1 x32),
  // 0x79 = 2^-6 (cancels w2eff x64)
  gemm_mx<0><<<4096, 256, 0, stream>>>(e8, w1T8, tc_b1, X8, nullptr, nullptr,
                                       2048, 1024, 0x7A7A7A7Au);
  gemm_mx<1><<<2048, 256, 0, stream>>>(X8, w2eT8, beff, nullptr, khg, kh0,
                                       1024, 2048, 0x79797979u);
  attn_kernel<<<512, 256, 0, stream>>>(khg, kh0, label, y, mask_text, qh);
  label_mlp<<<1024, 256, 0, stream>>>(qh, lh0, lhg, aw1, ab1, aw2, ab2, aw3, ab3,
                                      aw4, ab4, mask_label, out);
}

// Round 6
// 508.139 us; speedup vs baseline: 1.1238x; 1.0420x over previous
//
#include <hip/hip_runtime.h>
#include <stdint.h>

// ---------------------------------------------------------------------------
// MiniAlignDecoder on MI355X (gfx950)  — Round 10
// R10 changes vs R9 (529.5 µs; gemm steady 93.4 µs = structure ceiling,
// hidden kernels all < 93 µs; attacking invisible VALU cost, zero risk):
//  * facosh(): acoshf -> __logf(x + sqrt(x^2-1)) in attn (2.1M calls) and
//    label_mlp (4.2M calls). ~5x fewer instrs per call; error << fp8 noise.
//  * label_mlp: loop interchange (h/i-outer, o-inner) for w1/w2/w3 ->
//    contiguous 128 B weight rows per iteration (uniform s_load_dwordx4
//    instead of stride-128 scalar loads). Per-output accumulation order
//    unchanged (identical rounding).
//  * gemm_mx / prep / attn structure unchanged from R9 (verified).
// ---------------------------------------------------------------------------

typedef unsigned short u16;
typedef unsigned char u8;
typedef __attribute__((ext_vector_type(4))) float f32x4;
typedef __attribute__((ext_vector_type(4))) int i32x4;
typedef __attribute__((ext_vector_type(8))) int i32x8;

#define DEVI static __device__ __forceinline__

DEVI float bf2f(u16 u) { return __uint_as_float(((unsigned int)u) << 16); }
DEVI u16 f2bfbits(float f) {
  unsigned int x = __float_as_uint(f);
  unsigned int r = x + 0x7fffu + ((x >> 16) & 1u);   // RNE
  return (u16)(r >> 16);
}
DEVI u8 f2fp8(float f) {
  return (u8)(__builtin_amdgcn_cvt_pk_fp8_f32(f, 0.f, 0, false) & 0xff);
}
DEVI unsigned int pack4_fp8(float a, float b, float c, float d) {
  int r = __builtin_amdgcn_cvt_pk_fp8_f32(a, b, 0, false);
  r = __builtin_amdgcn_cvt_pk_fp8_f32(c, d, r, true);
  return (unsigned int)r;
}
// fast acosh for x >= 1+1e-6 (clamped upstream); |rel err| ~1e-7,
// negligible vs the fp8-GEMM noise floor (absmax 0.21)
DEVI float facosh(float x) {
  return __logf(x + __fsqrt_rn(fmaf(x, x, -1.f)));
}

typedef __attribute__((address_space(1))) unsigned int gu32;
typedef __attribute__((address_space(3))) unsigned int su32;
DEVI void lds_cp16(const void* g, void* l) {
  __builtin_amdgcn_global_load_lds((gu32*)g, (su32*)l, 16, 0, 0);
}

// ---------------------------------------------------------------------------
// prep: heterogeneous roles by blockIdx.x (unchanged from R9)
__global__ __launch_bounds__(256) void prep_kernel(
    const float* __restrict__ e, const float* __restrict__ w1,
    const float* __restrict__ w2, const float* __restrict__ b2,
    const float* __restrict__ hw, const float* __restrict__ hb,
    const float* __restrict__ label,
    u8* __restrict__ e8, u8* __restrict__ w1T8, u8* __restrict__ w2eT8,
    float* __restrict__ beff, u16* __restrict__ lh0, u16* __restrict__ lhg) {
  __shared__ float t[64][65];
  const int blk = blockIdx.x;
  const int tid = threadIdx.x;

  if (blk >= 673) {                       // ---- cvt e -> fp8
    int gi = (blk - 673) * 256 + tid;     // uint4 output index
    const float4* in = (const float4*)e + (size_t)gi * 4;
    float4 f0 = in[0], f1 = in[1], f2 = in[2], f3 = in[3];
    uint4 o;
    o.x = pack4_fp8(f0.x, f0.y, f0.z, f0.w);
    o.y = pack4_fp8(f1.x, f1.y, f1.z, f1.w);
    o.z = pack4_fp8(f2.x, f2.y, f2.z, f2.w);
    o.w = pack4_fp8(f3.x, f3.y, f3.z, f3.w);
    ((uint4*)e8)[gi] = o;
  } else if (blk < 512) {                 // ---- transpose w1 -> w1T8 (x32)
    int c0 = (blk & 31) * 64, r0 = (blk >> 5) * 64;
    int tx = tid & 63, ty = tid >> 6;
#pragma unroll
    for (int i = 0; i < 16; i++) {
      int r = i * 4 + ty;
      t[r][tx] = w1[(size_t)(r0 + r) * 2048 + c0 + tx];
    }
    __syncthreads();
#pragma unroll
    for (int i = 0; i < 16; i++) {
      int c = i * 4 + ty;
      w1T8[(size_t)(c0 + c) * 1024 + r0 + tx] = f2fp8(t[tx][c] * 32.f);
    }
  } else if (blk < 640) {                 // ---- w2eff (x64)
    int bw = blk - 512;
    int ch = bw >> 3, kb = bw & 7;
    int k = kb * 256 + tid;
    float row[64];
    const float4* rp = (const float4*)(w2 + (size_t)k * 1024 + ch * 64);
#pragma unroll
    for (int i = 0; i < 16; i++) {
      float4 f = rp[i];
      row[i * 4] = f.x; row[i * 4 + 1] = f.y; row[i * 4 + 2] = f.z; row[i * 4 + 3] = f.w;
    }
    for (int o = 0; o < 64; o++) {
      float a = 0.f;
#pragma unroll
      for (int d = 0; d < 64; d++) a = fmaf(row[d], hw[d * 64 + o], a);
      w2eT8[(size_t)(ch * 64 + o) * 2048 + k] = f2fp8(a * 64.f);
    }
  } else if (blk == 640) {                // ---- beff
    for (int n = tid; n < 1024; n += 256) {
      int ch = n >> 6, o = n & 63;
      float a = hb[o];
#pragma unroll
      for (int d = 0; d < 64; d++) a += b2[ch * 64 + d] * hw[d * 64 + o];
      beff[n] = a;
    }
  } else {                                // ---- lh (bf16, group-of-8 layout)
    int l = (blk - 641) * 256 + tid;
    const float4* lp = (const float4*)(label + (size_t)l * 64);
    float v[64]; float sq = 0.f;
#pragma unroll
    for (int i = 0; i < 16; i++) {
      float4 f = lp[i];
      v[i * 4] = f.x; v[i * 4 + 1] = f.y; v[i * 4 + 2] = f.z; v[i * 4 + 3] = f.w;
      sq += f.x * f.x + f.y * f.y + f.z * f.z + f.w * f.w;
    }
    float dd = fmaxf(1.f - sq, 1e-12f);
    lh0[l] = f2bfbits((1.f + sq) / dd);
    float sc = 2.f / dd;
#pragma unroll
    for (int g = 0; g < 8; g++) {
      unsigned int o0 = f2bfbits(v[8 * g + 0] * sc) | ((unsigned int)f2bfbits(v[8 * g + 1] * sc) << 16);
      unsigned int o1 = f2bfbits(v[8 * g + 2] * sc) | ((unsigned int)f2bfbits(v[8 * g + 3] * sc) << 16);
      unsigned int o2 = f2bfbits(v[8 * g + 4] * sc) | ((unsigned int)f2bfbits(v[8 * g + 5] * sc) << 16);
      unsigned int o3 = f2bfbits(v[8 * g + 6] * sc) | ((unsigned int)f2bfbits(v[8 * g + 7] * sc) << 16);
      ((uint4*)lhg)[(size_t)g * 8192 + l] = make_uint4(o0, o1, o2, o3);
    }
  }
}

// ---------------------------------------------------------------------------
// MX-scaled fp8 GEMM: K=128/iter, 128x128 tile, 4 waves (2x2), 4x4 MFMA
// 16x16x128 per wave. LDS rows 128 B with XOR 16B-chunk swizzle.
// (verified structure, 93.4 µs steady; do NOT re-pipeline: m132/R8 showed
// any 64-128 KB LDS variant drops occupancy 3->2/1 blocks/CU and loses)
// MODE 0: relu(acc+bias) -> C fp8.
// MODE 1: expmap0+hyperboloid -> khg (group-of-8 interleaved) + kh0.
template <int MODE>
__global__ __launch_bounds__(256, 4) void gemm_mx(
    const u8* __restrict__ A, const u8* __restrict__ Bt,
    const float* __restrict__ bias, u8* __restrict__ C,
    u16* __restrict__ khg, u16* __restrict__ kh0,
    int N, int K, unsigned int sb_scale) {
  __shared__ __attribute__((aligned(16))) u8 SM[32768];
  u8* As = SM;                 // [128][128] fp8, chunk-swizzled
  u8* Bs = SM + 16384;
  const int tid = threadIdx.x;
  const int wave = tid >> 6, lane = tid & 63;
  const int fr = lane & 15, q = lane >> 4;
  const int nblk = N >> 7;
  const int g = blockIdx.x;
  const int xcd = g & 7;
  const int t = g >> 3;
  const int per = (gridDim.x >> 3) / nblk;     // bm rows per XCD
  const int bm = xcd * per + t / nblk;
  const int bn = t % nblk;
  const size_t m0 = (size_t)bm * 128;
  const int n0 = bn * 128;
  const int wm = (wave >> 1) << 6, wn = (wave & 1) << 6;
  f32x4 acc[4][4] = {};

  // staging: call c covers rows [c*32, c*32+32); lane: row = c*32 + (tid>>3),
  // LDS pos = tid&7, source chunk = pos ^ (row&7)  (c*32 = 0 mod 8)
  const int srow = tid >> 3;
  const int schunk = (tid & 7) ^ (srow & 7);
  const u8* Ap = A + (m0 + srow) * (size_t)K + schunk * 16;
  const u8* Bp = Bt + ((size_t)n0 + srow) * K + schunk * 16;

  // fragment read base: row = wm|wn + t2*16 + fr (row&7 == fr&7), lane's
  // 32 K-bytes = chunks {2q, 2q+1} -> swizzled positions, hi = lo ^ 16
  const int aL = (wm + fr) * 128 + ((((q << 1)) ^ (fr & 7)) << 4);
  const int bL = (wn + fr) * 128 + ((((q << 1)) ^ (fr & 7)) << 4);

  for (int kk = 0; kk < K; kk += 128) {
#pragma unroll
    for (int c = 0; c < 4; c++) {
      lds_cp16(Ap + (size_t)c * 32 * K, As + c * 4096 + wave * 1024);
      lds_cp16(Bp + (size_t)c * 32 * K, Bs + c * 4096 + wave * 1024);
    }
    Ap += 128; Bp += 128;
    __syncthreads();   // staged data visible
    i32x8 af[4], bf[4];
#pragma unroll
    for (int t2 = 0; t2 < 4; t2++) {
      i32x4 lo = *(const i32x4*)(As + aL + t2 * 2048);
      i32x4 hi = *(const i32x4*)(As + (aL ^ 16) + t2 * 2048);
      af[t2] = __builtin_shufflevector(lo, hi, 0, 1, 2, 3, 4, 5, 6, 7);
      i32x4 lo2 = *(const i32x4*)(Bs + bL + t2 * 2048);
      i32x4 hi2 = *(const i32x4*)(Bs + (bL ^ 16) + t2 * 2048);
      bf[t2] = __builtin_shufflevector(lo2, hi2, 0, 1, 2, 3, 4, 5, 6, 7);
    }
#pragma unroll
    for (int i = 0; i < 4; i++)
#pragma unroll
      for (int j = 0; j < 4; j++)
        acc[i][j] = __builtin_amdgcn_mfma_scale_f32_16x16x128_f8f6f4(
            af[i], bf[j], acc[i][j], 0, 0,            // fmt A=fp8, fmt B=fp8
            0, 0x7F7F7F7F,                            // scale A = 2^0
            0, (int)sb_scale);                        // scale B (replicated)
    __syncthreads();   // all reads done before next stage overwrites
  }

  // C/D layout: col = n0+wn+j*16+fr, row = m0+wm+i*16+q*4+r  [m89-verified]
  if constexpr (MODE == 0) {
#pragma unroll
    for (int j = 0; j < 4; j++) {
      int col = n0 + wn + j * 16 + fr;
      float bv = bias[col];
#pragma unroll
      for (int i = 0; i < 4; i++) {
#pragma unroll
        for (int r = 0; r < 4; r++) {
          size_t row = m0 + wm + i * 16 + q * 4 + r;
          C[row * N + col] = f2fp8(fmaxf(acc[i][j][r] + bv, 0.f));
        }
      }
    }
  } else {
    // fused expmap0 + hyperboloid; wave's 64 cols = one full head.
    // Reuse SM (dead after K-loop's final barrier): ew = [4][16][66] u16
    // (one 16-comp j-pass per wave), k0w = [4][64] u16 at +9216.
    u16* ew = (u16*)SM;
    u16* k0w = (u16*)(SM + 9216);
    const int head = (n0 + wn) >> 6;
    const int rb = (int)m0 + wm;
    const int b = rb >> 10, s0 = rb & 1023;
    u16* gbase = khg + (size_t)(b * 16 + head) * 65536;   // [8][1024][8] u16
    float bv[4];
#pragma unroll
    for (int j = 0; j < 4; j++) bv[j] = bias[n0 + wn + j * 16 + fr];

    float ff[4][4];
#pragma unroll
    for (int i = 0; i < 4; i++) {
#pragma unroll
      for (int r = 0; r < 4; r++) {
        float v0 = acc[i][0][r] + bv[0];
        float v1 = acc[i][1][r] + bv[1];
        float v2 = acc[i][2][r] + bv[2];
        float v3 = acc[i][3][r] + bv[3];
        float ss = v0 * v0 + v1 * v1 + v2 * v2 + v3 * v3;
        ss += __shfl_xor(ss, 1); ss += __shfl_xor(ss, 2);
        ss += __shfl_xor(ss, 4); ss += __shfl_xor(ss, 8);  // 64-dim norm^2
        float n = sqrtf(fmaxf(ss, 1e-12f));
        float ex = __expf(-2.f * n);
        float th = (1.f - ex) / (1.f + ex);                // tanh(n)
        float sq = th * th;
        float dd = fmaxf(1.f - sq, 1e-12f);
        ff[i][r] = 2.f * (th / n) / dd;
        if (fr == 0) k0w[wave * 64 + i * 16 + q * 4 + r] = f2bfbits((1.f + sq) / dd);
      }
    }
#pragma unroll
    for (int j = 0; j < 4; j++) {
#pragma unroll
      for (int i = 0; i < 4; i++)
#pragma unroll
        for (int r = 0; r < 4; r++) {
          int trow = i * 16 + q * 4 + r;
          ew[wave * 1056 + fr * 66 + trow] =
              f2bfbits((acc[i][j][r] + bv[j]) * ff[i][r]);
        }
      __syncthreads();
      // store groups 2j, 2j+1: lane = row, one uint4 = 8 comps (coalesced,
      // 16 B/lane along consecutive s)
#pragma unroll
      for (int it = 0; it < 2; it++) {
        const u16* eb = ew + wave * 1056 + it * 8 * 66 + lane;
        unsigned int o0 = eb[0]   | ((unsigned int)eb[66]  << 16);
        unsigned int o1 = eb[132] | ((unsigned int)eb[198] << 16);
        unsigned int o2 = eb[264] | ((unsigned int)eb[330] << 16);
        unsigned int o3 = eb[396] | ((unsigned int)eb[462] << 16);
        *(uint4*)(gbase + ((size_t)(j * 2 + it) * 1024 + s0 + lane) * 8) =
            make_uint4(o0, o1, o2, o3);
      }
      __syncthreads();
    }
    if (lane < 32) {
      unsigned int dat = *(const unsigned int*)(k0w + wave * 64 + lane * 2);
      *(unsigned int*)(kh0 + (size_t)(b * 16 + head) * 1024 + s0 + lane * 2) = dat;
    }
  }
}

// ---------------------------------------------------------------------------
// attention, register-resident kh; preload is 32 uint4 + 4 u16 loads/thread
__global__ __launch_bounds__(256, 2) void attn_kernel(
    const u16* __restrict__ khg, const u16* __restrict__ kh0,
    const float* __restrict__ label,
    const int* __restrict__ y, const int* __restrict__ mask_text,
    float* __restrict__ qh_out) {
  const int g = blockIdx.x;
  const int b = (g & 7) * 4 + ((g >> 3) & 3);
  const int h = g >> 5;
  const int bh = b * 16 + h;
  const int tid = threadIdx.x, lane = tid & 63, wave = tid >> 6;
  __shared__ float qh[65], rtmp[4], redp[4][65];
  const u16* khb = khg + (size_t)bh * 65536;
  const u16* k0b = kh0 + (size_t)bh * 1024;

  float kh0r[4];
  unsigned int khp[4][32];    // khp[r][k] = (comp 2k+1) | (comp 2k+2)<<16
  int mt[4];
#pragma unroll
  for (int r = 0; r < 4; r++) {
    int s = r * 256 + tid;
    mt[r] = mask_text[b * 1024 + s];
    kh0r[r] = bf2f(k0b[s]);
#pragma unroll
    for (int gg = 0; gg < 8; gg++) {
      uint4 v = *(const uint4*)(khb + ((size_t)gg * 1024 + s) * 8);
      khp[r][gg * 4 + 0] = v.x;
      khp[r][gg * 4 + 1] = v.y;
      khp[r][gg * 4 + 2] = v.z;
      khp[r][gg * 4 + 3] = v.w;
    }
  }

  if (wave == 0) {                         // initial lift of q = label[y[b]]
    float qv = label[(size_t)y[b] * 64 + lane];
    float sq = qv * qv;
#pragma unroll
    for (int d = 1; d < 64; d <<= 1) sq += __shfl_xor(sq, d);
    float dd = fmaxf(1.f - sq, 1e-12f);
    qh[lane + 1] = 2.f * qv / dd;
    if (lane == 0) qh[0] = (1.f + sq) / dd;
  }
  __syncthreads();

  for (int layer = 0; layer < 4; layer++) {
    float q0 = qh[0];
    float inn[4];
#pragma unroll
    for (int r = 0; r < 4; r++) inn[r] = -q0 * kh0r[r];
#pragma unroll
    for (int k = 0; k < 32; k++) {
      float qa = qh[1 + 2 * k], qb = qh[2 + 2 * k];
#pragma unroll
      for (int r = 0; r < 4; r++) {
        unsigned int p = khp[r][k];
        inn[r] = fmaf(qa, __uint_as_float(p << 16),
                 fmaf(qb, __uint_as_float(p & 0xffff0000u), inn[r]));
      }
    }
    float w[4]; float lmax = -3e38f;
#pragma unroll
    for (int r = 0; r < 4; r++) {
      float x = fmaxf(-inn[r], 1.f + 1e-6f);
      float sco = -facosh(x);
      sco = (mt[r] > 0) ? sco : -1e9f;
      w[r] = sco;
      lmax = fmaxf(lmax, sco);
    }
#pragma unroll
    for (int d = 1; d < 64; d <<= 1) lmax = fmaxf(lmax, __shfl_xor(lmax, d));
    if (lane == 0) rtmp[wave] = lmax;
    __syncthreads();
    float m = fmaxf(fmaxf(rtmp[0], rtmp[1]), fmaxf(rtmp[2], rtmp[3]));
#pragma unroll
    for (int r = 0; r < 4; r++) w[r] = __expf(w[r] - m);

    float p0 = w[0] * kh0r[0] + w[1] * kh0r[1] + w[2] * kh0r[2] + w[3] * kh0r[3];
#pragma unroll
    for (int d = 1; d < 64; d <<= 1) p0 += __shfl_xor(p0, d);
    if (lane == 0) redp[wave][0] = p0;
#pragma unroll
    for (int k = 0; k < 32; k++) {
      float pa = 0.f, pb = 0.f;
#pragma unroll
      for (int r = 0; r < 4; r++) {
        unsigned int p = khp[r][k];
        pa = fmaf(w[r], __uint_as_float(p << 16), pa);
        pb = fmaf(w[r], __uint_as_float(p & 0xffff0000u), pb);
      }
#pragma unroll
      for (int d = 1; d < 64; d <<= 1) pa += __shfl_xor(pa, d);
#pragma unroll
      for (int d = 1; d < 64; d <<= 1) pb += __shfl_xor(pb, d);
      if (lane == 0) { redp[wave][1 + 2 * k] = pa; redp[wave][2 + 2 * k] = pb; }
    }
    __syncthreads();

    if (wave == 0) {                       // Einstein midpoint + k2p + lift
      float denom = redp[0][0] + redp[1][0] + redp[2][0] + redp[3][0];
      float num = redp[0][lane + 1] + redp[1][lane + 1] + redp[2][lane + 1] + redp[3][lane + 1];
      float mid = num / denom;             // Klein coords
      float kl = mid * mid;
#pragma unroll
      for (int d = 1; d < 64; d <<= 1) kl += __shfl_xor(kl, d);
      float u = sqrtf(fmaxf(1.f - kl, 1e-12f));
      float pc = mid / (1.f + u);
      float sp = kl / ((1.f + u) * (1.f + u));
      float dd = fmaxf(1.f - sp, 1e-12f);
      qh[lane + 1] = 2.f * pc / dd;
      if (lane == 0) qh[0] = (1.f + sp) / dd;
    }
    __syncthreads();
  }
  if (tid < 65) qh_out[(size_t)bh * 65 + tid] = qh[tid];
}

// ---------------------------------------------------------------------------
// label distances + aggregation MLP; lh loads are 8 uint4/thread.
// qT staged in LDS (R9); R10: fast acosh + loop-interchanged MLP so weight
// reads are contiguous rows (uniform s_load_dwordx4). Accumulation order
// per output is unchanged.
__global__ __launch_bounds__(256) void label_mlp(
    const float* __restrict__ qh, const u16* __restrict__ lh0,
    const u16* __restrict__ lhg,
    const float* __restrict__ w1, const float* __restrict__ b1,
    const float* __restrict__ w2, const float* __restrict__ b2,
    const float* __restrict__ w3, const float* __restrict__ b3,
    const float* __restrict__ w4, const float* __restrict__ b4,
    const int* __restrict__ mask_label, float* __restrict__ out) {
  __shared__ float qT[65][16];            // qT[c][h]
  int blk = blockIdx.x;
  int b = blk >> 5, lb = blk & 31;
  int l = lb * 256 + threadIdx.x;
  const float* qb = qh + (size_t)b * 1040;

  for (int i = threadIdx.x; i < 1040; i += 256) {
    int h = i / 65, c = i % 65;
    qT[c][h] = qb[i];                     // coalesced read, one-time scatter
  }
  __syncthreads();

  float inner[16];
  float l0 = bf2f(lh0[l]);
#pragma unroll
  for (int h = 0; h < 16; h++) inner[h] = -qT[0][h] * l0;
#pragma unroll
  for (int g = 0; g < 8; g++) {
    uint4 v = *(const uint4*)(lhg + ((size_t)g * 8192 + l) * 8);
    unsigned int pw[4] = {v.x, v.y, v.z, v.w};
#pragma unroll
    for (int p = 0; p < 4; p++) {
      int k = g * 4 + p;
      float la = __uint_as_float(pw[p] << 16);
      float lb2 = __uint_as_float(pw[p] & 0xffff0000u);
#pragma unroll
      for (int h = 0; h < 16; h++)
        inner[h] = fmaf(qT[1 + 2 * k][h], la,
                   fmaf(qT[2 + 2 * k][h], lb2, inner[h]));
    }
  }
  float d[16];
#pragma unroll
  for (int h = 0; h < 16; h++) d[h] = facosh(fmaxf(-inner[h], 1.f + 1e-6f));

  // x1 = relu(d @ w1 + b1): h-outer, o-inner -> w1 rows contiguous
  float x1[32];
#pragma unroll
  for (int o = 0; o < 32; o++) x1[o] = b1[o];
#pragma unroll
  for (int h = 0; h < 16; h++) {
    float dh = d[h];
#pragma unroll
    for (int o = 0; o < 32; o++) x1[o] = fmaf(dh, w1[h * 32 + o], x1[o]);
  }
#pragma unroll
  for (int o = 0; o < 32; o++) x1[o] = fmaxf(x1[o], 0.f);

  // x2 = relu(x1 @ w2 + b2)
  float x2[32];
#pragma unroll
  for (int o = 0; o < 32; o++) x2[o] = b2[o];
#pragma unroll
  for (int i = 0; i < 32; i++) {
    float xi = x1[i];
#pragma unroll
    for (int o = 0; o < 32; o++) x2[o] = fmaf(xi, w2[i * 32 + o], x2[o]);
  }
#pragma unroll
  for (int o = 0; o < 32; o++) x2[o] = fmaxf(x2[o], 0.f);

  // x3 = relu(x2 @ w3 + b3)
  float x3[16];
#pragma unroll
  for (int o = 0; o < 16; o++) x3[o] = b3[o];
#pragma unroll
  for (int i = 0; i < 32; i++) {
    float xi = x2[i];
#pragma unroll
    for (int o = 0; o < 16; o++) x3[o] = fmaf(xi, w3[i * 16 + o], x3[o]);
  }

  float acc = b4[0];
#pragma unroll
  for (int h = 0; h < 16; h++) acc = fmaf(fmaxf(x3[h], 0.f), w4[h], acc);
  out[(size_t)b * 8192 + l] = (mask_label[(size_t)b * 8192 + l] > 0) ? acc : -500.0f;
}

// ---------------------------------------------------------------------------
extern "C" void kernel_launch(void* const* d_in, const int* in_sizes, int n_in,
                              void* d_out, int out_size, void* d_ws, size_t ws_size,
                              hipStream_t stream) {
  const float* e     = (const float*)d_in[0];
  const float* label = (const float*)d_in[1];
  const float* tc_w1 = (const float*)d_in[2];
  const float* tc_b1 = (const float*)d_in[3];
  const float* tc_w2 = (const float*)d_in[4];
  const float* tc_b2 = (const float*)d_in[5];
  const float* hyp_w = (const float*)d_in[6];
  const float* hyp_b = (const float*)d_in[7];
  const float* aw1 = (const float*)d_in[8];
  const float* ab1 = (const float*)d_in[9];
  const float* aw2 = (const float*)d_in[10];
  const float* ab2 = (const float*)d_in[11];
  const float* aw3 = (const float*)d_in[12];
  const float* ab3 = (const float*)d_in[13];
  const float* aw4 = (const float*)d_in[14];
  const float* ab4 = (const float*)d_in[15];
  const int* y          = (const int*)d_in[16];
  const int* mask_text  = (const int*)d_in[17];
  const int* mask_label = (const int*)d_in[18];
  float* out = (float*)d_out;

  char* ws = (char*)d_ws;
  // [0, 67.1MB): X8 (fp8 32768x2048); qh (133KB) aliases it after gemm2
  // [67.1MB, 134.2MB): khg bf16 [512][8][1024][8] (comps 1..64 interleaved)
  // [134.2MB, 135.3MB): kh0 bf16 [512][1024]
  // [135.3MB, 168.8MB): e8 fp8 [32768][1024]
  u8*    X8    = (u8*)(ws + 0);
  float* qh    = (float*)(ws + 0);
  u16*   khg   = (u16*)(ws + 67108864ull);
  u16*   kh0   = (u16*)(ws + 134217728ull);
  u8*    e8    = (u8*)(ws + 135266304ull);
  u8*    w1T8  = (u8*)(ws + 168820736ull);
  u8*    w2eT8 = (u8*)(ws + 170917888ull);
  float* beff  = (float*)(ws + 173015040ull);
  u16*   lhg   = (u16*)(ws + 173019136ull);   // bf16 [8][8192][8] = 1.0MB
  u16*   lh0   = (u16*)(ws + 174067712ull);   // bf16 [8192] = 16KB

  prep_kernel<<<673 + 8192, 256, 0, stream>>>(e, tc_w1, tc_w2, tc_b2, hyp_w, hyp_b,
                                              label, e8, w1T8, w2eT8, beff, lh0, lhg);
  // scale B bytes (E8M0, replicated): 0x7A = 2^-5 (cancels w1 x32),
  // 0x79 = 2^-6 (cancels w2eff x64)
  gemm_mx<0><<<4096, 256, 0, stream>>>(e8, w1T8, tc_b1, X8, nullptr, nullptr,
                                       2048, 1024, 0x7A7A7A7Au);
  gemm_mx<1><<<2048, 256, 0, stream>>>(X8, w2eT8, beff, nullptr, khg, kh0,
                                       1024, 2048, 0x79797979u);
  attn_kernel<<<512, 256, 0, stream>>>(khg, kh0, label, y, mask_text, qh);
  label_mlp<<<1024, 256, 0, stream>>>(qh, lh0, lhg, aw1, ab1, aw2, ab2, aw3, ab3,
                                      aw4, ab4, mask_label, out);
}